// Round 3
// baseline (953.305 us; speedup 1.0000x reference)
//
#include <hip/hip_runtime.h>

#define B_ 2
#define S_ 2048
#define D_ 768
#define H_ 12
#define DK_ 64
#define BH_ (B_*H_)
#define NEGV (-1e9f)
#define SCALE 0.125f
#define MINIT (-1e30f)

typedef unsigned short u16;
typedef __attribute__((ext_vector_type(8))) short bf16x8;   // 8 bf16 (4 VGPRs)
typedef __attribute__((ext_vector_type(4))) float f32x4;    // MFMA accumulator

__device__ __forceinline__ u16 f2bf(float f){
  union { float f; unsigned int i; } v; v.f = f;
  unsigned int x = v.i;
  return (u16)((x + 0x7FFFu + ((x >> 16) & 1u)) >> 16);
}
// split f32 into bf16 hi (truncated) + bf16 lo (truncated residual); 3-term MFMA ~ f32 GEMM accuracy
__device__ __forceinline__ void split2(float x, u16& h, u16& l){
  const unsigned int xi = __float_as_uint(x);
  h = (u16)(xi >> 16);
  const float lo = x - __uint_as_float(xi & 0xFFFF0000u);   // exact (Sterbenz)
  l = (u16)(__float_as_uint(lo) >> 16);
}

#define XN_ ((size_t)4096*768)
#define WN_ ((size_t)768*768)

// ---------------- prep: pre-split X (q,k,v inputs) and Wq/Wk/Wv into bf16 hi/lo planes ----------------
// scratch layout (u16): Xh[z]=z*XN, Xl[z]=(3+z)*XN, Wh[z]=6XN+z*WN, Wl[z]=6XN+3WN+z*WN  (44.8 MB)
__global__ __launch_bounds__(256) void prep(
    const float* __restrict__ Xq, const float* __restrict__ Xk, const float* __restrict__ Xv,
    const float* __restrict__ Wq, const float* __restrict__ Wk, const float* __restrict__ Wv,
    u16* __restrict__ scr)
{
  const int a = blockIdx.y;  // 0..5
  const float* src; u16* h; u16* l; size_t n;
  if (a < 3){
    src = (a==0)?Xq:(a==1)?Xk:Xv;
    h = scr + (size_t)a*XN_;  l = scr + (size_t)(3+a)*XN_;  n = XN_;
  } else {
    const int z = a-3;
    src = (z==0)?Wq:(z==1)?Wk:Wv;
    h = scr + 6*XN_ + (size_t)z*WN_;  l = scr + 6*XN_ + 3*WN_ + (size_t)z*WN_;  n = WN_;
  }
  const size_t nv = n >> 2;
  for (size_t i = (size_t)blockIdx.x*256 + threadIdx.x; i < nv; i += (size_t)gridDim.x*256){
    float4 v = ((const float4*)src)[i];
    ushort4 hv, lv;
    split2(v.x,hv.x,lv.x); split2(v.y,hv.y,lv.y); split2(v.z,hv.z,lv.z); split2(v.w,hv.w,lv.w);
    ((ushort4*)h)[i] = hv;  ((ushort4*)l)[i] = lv;
  }
}

// ---------------- MFMA GEMM: C[r,c] = sum_k A[r,k]*B[c,k] (+bias), K=768 ----------------
// 128x128 tile, 4 waves (2x2), wave = 64x64 out = 4x4 frags of 16x16x32 bf16 MFMA.
// ALO: A has lo plane (3-term). BPRE: B pre-split bf16 planes; else B = f32, split in-kernel (2/3-term).
// OMODE: 0 = f32 plain [M,768]; 1 = bf16 head-split [bh][s][dk]; 2 = bf16 V^T [bh][dk][s] (A=W,B=X)
template<bool ALO, bool BPRE, int OMODE>
__device__ __forceinline__ void gemmM(const u16* __restrict__ Ah_, const u16* __restrict__ Al_,
                                      const u16* __restrict__ Bh_, const u16* __restrict__ Bl_,
                                      const float* __restrict__ Bf_,
                                      const float* __restrict__ bias, void* __restrict__ outp)
{
  const int bx = blockIdx.x, by = blockIdx.y;
  const int tid  = threadIdx.x;
  const int lane = tid & 63;
  const int w    = tid >> 6;
  const int g    = lane >> 4;
  const int c    = lane & 15;
  const int wr   = w >> 1, wc = w & 1;

  __shared__ u16 Ah[128][36];
  __shared__ u16 Al[128][36];
  __shared__ u16 Bh[128][36];
  __shared__ u16 Bl[128][36];

  const int ar0 = (OMODE==2 ? by : bx) * 128;
  const int br0 = (OMODE==2 ? bx : by) * 128;

  uint4 rah[2], ral[2], rbh[2], rbl[2];
  float4 rbf[4];

  auto ldplane = [&](uint4* r, const u16* base, int rbase, int k0){
    #pragma unroll
    for (int i=0;i<2;i++){
      const int ci = tid + i*256;
      const int row = ci >> 2, c8 = (ci & 3)*8;
      r[i] = *(const uint4*)(base + (size_t)(rbase+row)*D_ + k0 + c8);
    }
  };
  auto stplane = [&](u16 (*P)[36], const uint4* r){
    #pragma unroll
    for (int i=0;i<2;i++){
      const int ci = tid + i*256;
      const int row = ci >> 2, c8 = (ci & 3)*8;
      *(uint4*)&P[row][c8] = r[i];
    }
  };
  auto ldBf = [&](int k0){
    #pragma unroll
    for (int i=0;i<4;i++){
      const int ci = tid + i*256;
      const int row = ci >> 3, c4 = (ci & 7)*4;
      rbf[i] = *(const float4*)(Bf_ + (size_t)(br0+row)*D_ + k0 + c4);
    }
  };
  auto stBf = [&](){
    #pragma unroll
    for (int i=0;i<4;i++){
      const int ci = tid + i*256;
      const int row = ci >> 3, c4 = (ci & 7)*4;
      ushort4 hv, lv;
      split2(rbf[i].x,hv.x,lv.x); split2(rbf[i].y,hv.y,lv.y);
      split2(rbf[i].z,hv.z,lv.z); split2(rbf[i].w,hv.w,lv.w);
      *(ushort4*)&Bh[row][c4] = hv;  *(ushort4*)&Bl[row][c4] = lv;
    }
  };

  f32x4 acc[4][4];
  #pragma unroll
  for (int m=0;m<4;m++)
    #pragma unroll
    for (int n=0;n<4;n++) acc[m][n] = (f32x4){0.f,0.f,0.f,0.f};

  // prologue loads (tile 0)
  ldplane(rah, Ah_, ar0, 0);
  if constexpr (ALO) ldplane(ral, Al_, ar0, 0);
  if constexpr (BPRE){ ldplane(rbh, Bh_, br0, 0); ldplane(rbl, Bl_, br0, 0); } else ldBf(0);

  for (int t=0; t<D_/32; ++t){
    __syncthreads();                      // prev compute done
    stplane(Ah, rah);
    if constexpr (ALO) stplane(Al, ral);
    if constexpr (BPRE){ stplane(Bh, rbh); stplane(Bl, rbl); } else stBf();
    if (t < D_/32 - 1){
      const int k0n = (t+1)*32;           // issue next-tile loads; latency hides under MFMA
      ldplane(rah, Ah_, ar0, k0n);
      if constexpr (ALO) ldplane(ral, Al_, ar0, k0n);
      if constexpr (BPRE){ ldplane(rbh, Bh_, br0, k0n); ldplane(rbl, Bl_, br0, k0n); } else ldBf(k0n);
    }
    __syncthreads();                      // tile visible

    bf16x8 ah[4], al[4], bh[4], bl[4];
    #pragma unroll
    for (int m=0;m<4;m++){
      ah[m] = *(const bf16x8*)&Ah[wr*64 + m*16 + c][g*8];
      if constexpr (ALO) al[m] = *(const bf16x8*)&Al[wr*64 + m*16 + c][g*8];
    }
    #pragma unroll
    for (int n=0;n<4;n++){
      bh[n] = *(const bf16x8*)&Bh[wc*64 + n*16 + c][g*8];
      bl[n] = *(const bf16x8*)&Bl[wc*64 + n*16 + c][g*8];
    }
    #pragma unroll
    for (int m=0;m<4;m++)
      #pragma unroll
      for (int n=0;n<4;n++){
        acc[m][n] = __builtin_amdgcn_mfma_f32_16x16x32_bf16(ah[m], bh[n], acc[m][n], 0,0,0);
        acc[m][n] = __builtin_amdgcn_mfma_f32_16x16x32_bf16(ah[m], bl[n], acc[m][n], 0,0,0);
        if constexpr (ALO)
          acc[m][n] = __builtin_amdgcn_mfma_f32_16x16x32_bf16(al[m], bh[n], acc[m][n], 0,0,0);
      }
  }

  // ---- epilogue (C layout: col=lane&15, row=(lane>>4)*4+reg) ----
  if constexpr (OMODE==0) {
    float* out = (float*)outp;
    float bb[4];
    #pragma unroll
    for (int n=0;n<4;n++) bb[n] = bias[br0 + wc*64 + n*16 + c];
    #pragma unroll
    for (int m=0;m<4;m++)
      #pragma unroll
      for (int r=0;r<4;r++){
        const int rg = ar0 + wr*64 + m*16 + g*4 + r;
        #pragma unroll
        for (int n=0;n<4;n++)
          out[(size_t)rg*D_ + br0 + wc*64 + n*16 + c] = acc[m][n][r] + bb[n];
      }
  } else if constexpr (OMODE==1) {
    u16* out = (u16*)outp;
    float bb[4];
    #pragma unroll
    for (int n=0;n<4;n++) bb[n] = bias[br0 + wc*64 + n*16 + c];
    #pragma unroll
    for (int m=0;m<4;m++)
      #pragma unroll
      for (int r=0;r<4;r++){
        const int rg = ar0 + wr*64 + m*16 + g*4 + r;
        const int batch = rg >> 11, s = rg & (S_-1);
        #pragma unroll
        for (int n=0;n<4;n++){
          const int col = br0 + wc*64 + n*16 + c;
          const int hh = col >> 6, dk = col & 63;
          out[((size_t)(batch*H_ + hh)*S_ + s)*DK_ + dk] = f2bf(acc[m][n][r] + bb[n]);
        }
      }
  } else {  // OMODE==2: V^T [bh][dk][s]
    u16* out = (u16*)outp;
    #pragma unroll
    for (int m=0;m<4;m++)
      #pragma unroll
      for (int r=0;r<4;r++){
        const int dkg = ar0 + wr*64 + m*16 + g*4 + r;   // over W rows (768)
        const int hh = dkg >> 6, dkl = dkg & 63;
        const float bb = bias[dkg];
        #pragma unroll
        for (int n=0;n<4;n++){
          const int sg = br0 + wc*64 + n*16 + c;        // over X rows (4096)
          const int batch = sg >> 11, s = sg & (S_-1);
          out[((size_t)(batch*H_ + hh)*DK_ + dkl)*S_ + s] = f2bf(acc[m][n][r] + bb);
        }
      }
  }
}

__global__ __launch_bounds__(256,2) void proj_qkv(
    const u16* __restrict__ scr,
    const float* __restrict__ bq, const float* __restrict__ bk, const float* __restrict__ bv,
    u16* __restrict__ qkv)
{
  const int z = blockIdx.z;
  u16* out = qkv + (size_t)z * ((size_t)BH_*S_*DK_);
  const u16* Xh = scr + (size_t)z*XN_;
  const u16* Xl = scr + (size_t)(3+z)*XN_;
  const u16* Wh = scr + 6*XN_ + (size_t)z*WN_;
  const u16* Wl = scr + 6*XN_ + 3*WN_ + (size_t)z*WN_;
  const float* bias = (z==0)?bq:(z==1)?bk:bv;
  if (z==2) gemmM<true,true,2>(Wh, Wl, Xh, Xl, nullptr, bias, (void*)out);
  else      gemmM<true,true,1>(Xh, Xl, Wh, Wl, nullptr, bias, (void*)out);
}

__global__ __launch_bounds__(256,2) void proj_o(
    const u16* __restrict__ Xc, const float* __restrict__ Wo, const float* __restrict__ bo,
    float* __restrict__ out)
{
  gemmM<false,false,0>(Xc, nullptr, nullptr, nullptr, Wo, bo, (void*)out);
}

// ---------------- attention (MFMA, double-buffered, 1 barrier/tile) ----------------
__device__ __forceinline__ void loadT(uint4* r, const u16* __restrict__ src, size_t sstride, int tid){
  #pragma unroll
  for (int i=0;i<2;i++){
    const int ci = tid + i*256;
    const int row = ci >> 3, cc = (ci & 7) << 3;
    r[i] = *(const uint4*)(src + (size_t)row*sstride + cc);
  }
}
__device__ __forceinline__ void writeT(u16 (*dst)[72], const uint4* r, int tid){
  #pragma unroll
  for (int i=0;i<2;i++){
    const int ci = tid + i*256;
    const int row = ci >> 3, cc = (ci & 7) << 3;
    *(uint4*)&dst[row][cc] = r[i];
  }
}

__global__ __launch_bounds__(256,3) void attn(const u16* __restrict__ qkv, const int* __restrict__ mask,
                                              float* __restrict__ la, u16* __restrict__ ctx)
{
  const int bh = blockIdx.y;
  const int q0 = blockIdx.x * 64;
  const int b = bh / H_;
  const int h = bh - b*H_;
  const u16* Qp = qkv + (size_t)bh * S_ * DK_;             // [S][DK]
  const u16* Kp = qkv + (size_t)(BH_ + bh) * S_ * DK_;     // [S][DK]
  const u16* Vt = qkv + (size_t)(2*BH_ + bh) * S_ * DK_;   // [DK][S]
  const int* Mp = mask + (size_t)b * S_ * S_;

  const int tid  = threadIdx.x;
  const int w    = tid >> 6;
  const int lane = tid & 63;
  const int g    = lane >> 4;
  const int c    = lane & 15;

  __shared__ u16 KsB[2][64][72];
  __shared__ u16 VsB[2][64][72];
  __shared__ u16 Ps[4][16][72];    // wave-private strips -> no barrier needed around use

  // ---- Q -> VsB[0] (temp), read A-fragments ----
  {
    uint4 qr[2];
    loadT(qr, Qp + (size_t)q0*DK_, DK_, tid);
    writeT(VsB[0], qr, tid);
  }
  __syncthreads();
  const bf16x8 qf0 = *(const bf16x8*)&VsB[0][w*16 + c][g*8];
  const bf16x8 qf1 = *(const bf16x8*)&VsB[0][w*16 + c][g*8 + 32];

  float mt[4], lt[4];
  #pragma unroll
  for (int r=0;r<4;r++){ mt[r] = MINIT; lt[r] = 0.f; }

  // ---- pass A: online (m,l), K double-buffered, 1 barrier/tile ----
  {
    uint4 kr[2];
    loadT(kr, Kp, DK_, tid);
    writeT(KsB[0], kr, tid);                     // vmcnt auto
    for (int t=0; t<S_/64; ++t){
      __syncthreads();                           // KsB[t&1] visible; prev reads of KsB[(t+1)&1] done
      if (t < S_/64-1) loadT(kr, Kp + (size_t)(t+1)*64*DK_, DK_, tid);
      const u16 (*KT)[72] = KsB[t&1];
      f32x4 sc[4];
      #pragma unroll
      for (int nt=0; nt<4; nt++){
        const bf16x8 kf0 = *(const bf16x8*)&KT[nt*16 + c][g*8];
        const bf16x8 kf1 = *(const bf16x8*)&KT[nt*16 + c][g*8 + 32];
        f32x4 z = {0.f,0.f,0.f,0.f};
        z      = __builtin_amdgcn_mfma_f32_16x16x32_bf16(qf0, kf0, z, 0,0,0);
        sc[nt] = __builtin_amdgcn_mfma_f32_16x16x32_bf16(qf1, kf1, z, 0,0,0);
      }
      #pragma unroll
      for (int r=0;r<4;r++){
        const int qi = q0 + w*16 + g*4 + r;
        const int* mp = Mp + (size_t)qi*S_ + (size_t)t*64 + c;
        float sv[4];
        #pragma unroll
        for (int nt=0;nt<4;nt++)
          sv[nt] = mp[nt*16] ? sc[nt][r]*SCALE : NEGV;
        const float cm = fmaxf(fmaxf(sv[0],sv[1]), fmaxf(sv[2],sv[3]));
        if (!__all(cm <= mt[r])){                // exact defer: rescale only if any lane's max grew
          const float mn = fmaxf(mt[r], cm);
          lt[r] *= __expf(mt[r]-mn);
          mt[r] = mn;
        }
        lt[r] += __expf(sv[0]-mt[r]) + __expf(sv[1]-mt[r])
               + __expf(sv[2]-mt[r]) + __expf(sv[3]-mt[r]);
      }
      if (t < S_/64-1) writeT(KsB[(t+1)&1], kr, tid);   // other buffer; safe post-barrier
    }
  }

  // ---- merge (m,l) across the 16 lanes of each group ----
  float ml[4];
  #pragma unroll
  for (int r=0;r<4;r++){
    float m = mt[r], l = lt[r];
    #pragma unroll
    for (int st=1; st<16; st<<=1){
      const float m2 = __shfl_xor(m, st);
      const float l2 = __shfl_xor(l, st);
      const float mn = fmaxf(m, m2);
      l = l*__expf(m-mn) + l2*__expf(m2-mn);
      m = mn;
    }
    ml[r] = m + __logf(fmaxf(l, 1e-30f));
  }

  // ---- pass B: recompute scores, emit log_attn, MFMA P.V; K/V double-buffered ----
  f32x4 o[4];
  #pragma unroll
  for (int nt=0;nt<4;nt++) o[nt] = (f32x4){0.f,0.f,0.f,0.f};

  {
    uint4 kr[2], vr[2];
    loadT(kr, Kp, DK_, tid);
    loadT(vr, Vt, S_, tid);
    writeT(KsB[0], kr, tid);                    // safe: last KsB[0]/VsB[0] reads were before a barrier
    writeT(VsB[0], vr, tid);
    for (int t=0; t<S_/64; ++t){
      __syncthreads();
      if (t < S_/64-1){
        loadT(kr, Kp + (size_t)(t+1)*64*DK_, DK_, tid);
        loadT(vr, Vt + (size_t)(t+1)*64, S_, tid);
      }
      const u16 (*KT)[72] = KsB[t&1];
      const u16 (*VT)[72] = VsB[t&1];
      f32x4 sc[4];
      #pragma unroll
      for (int nt=0; nt<4; nt++){
        const bf16x8 kf0 = *(const bf16x8*)&KT[nt*16 + c][g*8];
        const bf16x8 kf1 = *(const bf16x8*)&KT[nt*16 + c][g*8 + 32];
        f32x4 z = {0.f,0.f,0.f,0.f};
        z      = __builtin_amdgcn_mfma_f32_16x16x32_bf16(qf0, kf0, z, 0,0,0);
        sc[nt] = __builtin_amdgcn_mfma_f32_16x16x32_bf16(qf1, kf1, z, 0,0,0);
      }
      float lvv[4][4];
      #pragma unroll
      for (int r=0;r<4;r++){
        const int qi = q0 + w*16 + g*4 + r;
        const int* mp = Mp + (size_t)qi*S_ + (size_t)t*64 + c;
        #pragma unroll
        for (int nt=0;nt<4;nt++){
          const float s  = mp[nt*16] ? sc[nt][r]*SCALE : NEGV;
          const float lv = fminf(s - ml[r], 0.f);
          lvv[r][nt] = lv;
          Ps[w][g*4+r][nt*16 + c] = f2bf(__expf(lv));
        }
      }
      // wave-private Ps: per-wave DS ordering + compiler lgkmcnt make this safe without barrier
      const bf16x8 pf0 = *(const bf16x8*)&Ps[w][c][g*8];
      const bf16x8 pf1 = *(const bf16x8*)&Ps[w][c][g*8 + 32];
      #pragma unroll
      for (int nt=0; nt<4; nt++){
        const bf16x8 vf0 = *(const bf16x8*)&VT[nt*16 + c][g*8];
        const bf16x8 vf1 = *(const bf16x8*)&VT[nt*16 + c][g*8 + 32];
        o[nt] = __builtin_amdgcn_mfma_f32_16x16x32_bf16(pf0, vf0, o[nt], 0,0,0);
        o[nt] = __builtin_amdgcn_mfma_f32_16x16x32_bf16(pf1, vf1, o[nt], 0,0,0);
      }
      #pragma unroll
      for (int r=0;r<4;r++){
        const int qi = q0 + w*16 + g*4 + r;
        float* lrow = la + ((size_t)bh*S_ + qi)*S_ + (size_t)t*64 + c;
        #pragma unroll
        for (int nt=0;nt<4;nt++) lrow[nt*16] = lvv[r][nt];
      }
      if (t < S_/64-1){
        writeT(KsB[(t+1)&1], kr, tid);
        writeT(VsB[(t+1)&1], vr, tid);
      }
    }
  }

  #pragma unroll
  for (int r=0;r<4;r++){
    const int qi = q0 + w*16 + g*4 + r;
    u16* crow = ctx + ((size_t)b*S_ + qi)*D_ + h*DK_ + c;
    #pragma unroll
    for (int nt=0;nt<4;nt++) crow[nt*16] = f2bf(o[nt][r]);
  }
}

extern "C" void kernel_launch(void* const* d_in, const int* in_sizes, int n_in,
                              void* d_out, int out_size, void* d_ws, size_t ws_size,
                              hipStream_t stream)
{
  const float* query = (const float*)d_in[0];
  const float* key   = (const float*)d_in[1];
  const float* value = (const float*)d_in[2];
  const int* mask    = (const int*)d_in[3];
  const float* Wq = (const float*)d_in[4];  const float* bq = (const float*)d_in[5];
  const float* Wk = (const float*)d_in[6];  const float* bk = (const float*)d_in[7];
  const float* Wv = (const float*)d_in[8];  const float* bv = (const float*)d_in[9];
  const float* Wo = (const float*)d_in[10]; const float* bo = (const float*)d_in[11];

  float* out = (float*)d_out;                      // [B,S,D] f32
  float* la  = out + (size_t)B_*S_*D_;             // [B,H,S,S] f32
  u16* qkvws = (u16*)d_ws;                         // Q,K: [BH,S,DK]; V: [BH,DK,S] bf16
  u16* ctx = qkvws + (size_t)3*BH_*S_*DK_;         // [B,S,D] bf16
  // scratch for pre-split planes lives in the la region (44.8 MB of 402 MB);
  // consumed by proj_qkv BEFORE attn overwrites la — same-stream ordering makes this safe.
  u16* scr = (u16*)la;

  prep    <<<dim3(768,6,1),  dim3(256,1,1), 0, stream>>>(query,key,value,Wq,Wk,Wv,scr);
  proj_qkv<<<dim3(32,6,3),   dim3(256,1,1), 0, stream>>>(scr, bq,bk,bv, qkvws);
  attn    <<<dim3(S_/64,BH_,1), dim3(256,1,1), 0, stream>>>(qkvws, mask, la, ctx);
  proj_o  <<<dim3(32,6,1),   dim3(256,1,1), 0, stream>>>(ctx, Wo, bo, out);
}

// Round 4
// 648.240 us; speedup vs baseline: 1.4706x; 1.4706x over previous
//
#include <hip/hip_runtime.h>

#define B_ 2
#define S_ 2048
#define D_ 768
#define H_ 12
#define DK_ 64
#define BH_ (B_*H_)
#define NEGV (-1e9f)
#define SCALE 0.125f
#define MINIT (-1e30f)

typedef unsigned short u16;
typedef unsigned long long u64;
typedef __attribute__((ext_vector_type(8))) short bf16x8;   // 8 bf16 (4 VGPRs)
typedef __attribute__((ext_vector_type(4))) float f32x4;    // MFMA accumulator

__device__ __forceinline__ u16 f2bf(float f){
  union { float f; unsigned int i; } v; v.f = f;
  unsigned int x = v.i;
  return (u16)((x + 0x7FFFu + ((x >> 16) & 1u)) >> 16);
}
// split f32 into bf16 hi (truncated) + bf16 lo (truncated residual); 3-term MFMA ~ f32 GEMM accuracy
__device__ __forceinline__ void split2(float x, u16& h, u16& l){
  const unsigned int xi = __float_as_uint(x);
  h = (u16)(xi >> 16);
  const float lo = x - __uint_as_float(xi & 0xFFFF0000u);   // exact (Sterbenz)
  l = (u16)(__float_as_uint(lo) >> 16);
}

#define XN_ ((size_t)4096*768)
#define WN_ ((size_t)768*768)

// ---------------- prep: pre-split X (q,k,v inputs) and Wq/Wk/Wv into bf16 hi/lo planes ----------------
// scratch (u16, in la region): Xh[z]=z*XN, Xl[z]=(3+z)*XN, Wh[z]=6XN+z*WN, Wl[z]=6XN+3WN+z*WN
__global__ __launch_bounds__(256) void prep(
    const float* __restrict__ Xq, const float* __restrict__ Xk, const float* __restrict__ Xv,
    const float* __restrict__ Wq, const float* __restrict__ Wk, const float* __restrict__ Wv,
    u16* __restrict__ scr)
{
  const int a = blockIdx.y;  // 0..5
  const float* src; u16* h; u16* l; size_t n;
  if (a < 3){
    src = (a==0)?Xq:(a==1)?Xk:Xv;
    h = scr + (size_t)a*XN_;  l = scr + (size_t)(3+a)*XN_;  n = XN_;
  } else {
    const int z = a-3;
    src = (z==0)?Wq:(z==1)?Wk:Wv;
    h = scr + 6*XN_ + (size_t)z*WN_;  l = scr + 6*XN_ + 3*WN_ + (size_t)z*WN_;  n = WN_;
  }
  const size_t nv = n >> 2;
  for (size_t i = (size_t)blockIdx.x*256 + threadIdx.x; i < nv; i += (size_t)gridDim.x*256){
    float4 v = ((const float4*)src)[i];
    ushort4 hv, lv;
    split2(v.x,hv.x,lv.x); split2(v.y,hv.y,lv.y); split2(v.z,hv.z,lv.z); split2(v.w,hv.w,lv.w);
    ((ushort4*)h)[i] = hv;  ((ushort4*)l)[i] = lv;
  }
}

// ---------------- maskpack: int32 mask [B,S,S] -> u64 bitmap [B,S,S/64] (1 MB, L2-resident) ----------
__global__ __launch_bounds__(256) void maskpack(const int* __restrict__ mask, u64* __restrict__ mbits){
  const size_t nw = (size_t)B_*S_*(S_/64);
  for (size_t wi = (size_t)blockIdx.x*256 + threadIdx.x; wi < nw; wi += (size_t)gridDim.x*256){
    const int* mp = mask + wi*64;
    u64 v = 0;
    #pragma unroll
    for (int j=0;j<64;j+=4){
      int4 m4 = *(const int4*)(mp + j);
      v |= ((u64)(m4.x!=0) << j)     | ((u64)(m4.y!=0) << (j+1))
         | ((u64)(m4.z!=0) << (j+2)) | ((u64)(m4.w!=0) << (j+3));
    }
    mbits[wi] = v;
  }
}

// ---------------- MFMA GEMM: C[r,c] = sum_k A[r,k]*B[c,k] (+bias), K=768 ----------------
// 128x128 tile, 4 waves (2x2), wave = 64x64 out = 4x4 frags of 16x16x32 bf16 MFMA.
// ALO: A has lo plane (3-term). BPRE: B pre-split bf16 planes; else B f32, split in-kernel.
// OMODE: 0 = f32 plain [M,768]; 1 = bf16 head-split [bh][s][dk]; 2 = bf16 V^T [bh][dk][s] (A=W,B=X)
// All staging goes through NAMED registers (no address-taken arrays -> no scratch).
template<bool ALO, bool BPRE, int OMODE>
__device__ __forceinline__ void gemmM(const u16* __restrict__ Ah_, const u16* __restrict__ Al_,
                                      const u16* __restrict__ Bh_, const u16* __restrict__ Bl_,
                                      const float* __restrict__ Bf_,
                                      const float* __restrict__ bias, void* __restrict__ outp)
{
  const int bx = blockIdx.x, by = blockIdx.y;
  const int tid  = threadIdx.x;
  const int lane = tid & 63;
  const int w    = tid >> 6;
  const int g    = lane >> 4;
  const int c    = lane & 15;
  const int wr   = w >> 1, wc = w & 1;

  __shared__ u16 Ah[128][36];
  __shared__ u16 Al[128][36];
  __shared__ u16 Bh[128][36];
  __shared__ u16 Bl[128][36];

  const int ar0 = (OMODE==2 ? by : bx) * 128;
  const int br0 = (OMODE==2 ? bx : by) * 128;

  // bf16-plane staging coords: 512 chunks of 8 u16 over 256 threads
  const int prow = tid >> 2;          // 0..63
  const int pcol = (tid & 3) * 8;     // 0,8,16,24
  // f32 staging coords: 1024 chunks of 4 f32 over 256 threads
  const int frow = tid >> 3;          // 0..31
  const int fcol = (tid & 7) * 4;     // 0..28

  uint4 rAh0, rAh1, rAl0, rAl1, rBh0, rBh1, rBl0, rBl1;
  float4 rf0, rf1, rf2, rf3;

  f32x4 acc[4][4];
  #pragma unroll
  for (int m=0;m<4;m++)
    #pragma unroll
    for (int n=0;n<4;n++) acc[m][n] = (f32x4){0.f,0.f,0.f,0.f};

#define LD_TILE(k0) do{ \
    rAh0 = *(const uint4*)(Ah_ + (size_t)(ar0+prow)*D_ + (k0) + pcol); \
    rAh1 = *(const uint4*)(Ah_ + (size_t)(ar0+64+prow)*D_ + (k0) + pcol); \
    if constexpr (ALO){ \
      rAl0 = *(const uint4*)(Al_ + (size_t)(ar0+prow)*D_ + (k0) + pcol); \
      rAl1 = *(const uint4*)(Al_ + (size_t)(ar0+64+prow)*D_ + (k0) + pcol); } \
    if constexpr (BPRE){ \
      rBh0 = *(const uint4*)(Bh_ + (size_t)(br0+prow)*D_ + (k0) + pcol); \
      rBh1 = *(const uint4*)(Bh_ + (size_t)(br0+64+prow)*D_ + (k0) + pcol); \
      rBl0 = *(const uint4*)(Bl_ + (size_t)(br0+prow)*D_ + (k0) + pcol); \
      rBl1 = *(const uint4*)(Bl_ + (size_t)(br0+64+prow)*D_ + (k0) + pcol); \
    } else { \
      rf0 = *(const float4*)(Bf_ + (size_t)(br0+frow)*D_ + (k0) + fcol); \
      rf1 = *(const float4*)(Bf_ + (size_t)(br0+32+frow)*D_ + (k0) + fcol); \
      rf2 = *(const float4*)(Bf_ + (size_t)(br0+64+frow)*D_ + (k0) + fcol); \
      rf3 = *(const float4*)(Bf_ + (size_t)(br0+96+frow)*D_ + (k0) + fcol); \
    } }while(0)

#define ST_F32(rf, rofs) do{ \
    ushort4 hv, lv; \
    split2((rf).x,hv.x,lv.x); split2((rf).y,hv.y,lv.y); \
    split2((rf).z,hv.z,lv.z); split2((rf).w,hv.w,lv.w); \
    *(ushort4*)&Bh[(rofs)+frow][fcol] = hv;  *(ushort4*)&Bl[(rofs)+frow][fcol] = lv; }while(0)

#define ST_TILE() do{ \
    *(uint4*)&Ah[prow][pcol] = rAh0;  *(uint4*)&Ah[prow+64][pcol] = rAh1; \
    if constexpr (ALO){ *(uint4*)&Al[prow][pcol] = rAl0; *(uint4*)&Al[prow+64][pcol] = rAl1; } \
    if constexpr (BPRE){ \
      *(uint4*)&Bh[prow][pcol] = rBh0;  *(uint4*)&Bh[prow+64][pcol] = rBh1; \
      *(uint4*)&Bl[prow][pcol] = rBl0;  *(uint4*)&Bl[prow+64][pcol] = rBl1; \
    } else { ST_F32(rf0,0); ST_F32(rf1,32); ST_F32(rf2,64); ST_F32(rf3,96); } }while(0)

  LD_TILE(0);

  for (int t=0; t<D_/32; ++t){
    __syncthreads();                      // previous tile's LDS reads complete
    ST_TILE();
    if (t < D_/32 - 1) LD_TILE((t+1)*32); // in flight across the compute phase
    __syncthreads();                      // tile visible

    bf16x8 fah[4], fal[4], fbh[4], fbl[4];
    #pragma unroll
    for (int m=0;m<4;m++){
      fah[m] = *(const bf16x8*)&Ah[wr*64 + m*16 + c][g*8];
      if constexpr (ALO) fal[m] = *(const bf16x8*)&Al[wr*64 + m*16 + c][g*8];
    }
    #pragma unroll
    for (int n=0;n<4;n++){
      fbh[n] = *(const bf16x8*)&Bh[wc*64 + n*16 + c][g*8];
      fbl[n] = *(const bf16x8*)&Bl[wc*64 + n*16 + c][g*8];
    }
    #pragma unroll
    for (int m=0;m<4;m++)
      #pragma unroll
      for (int n=0;n<4;n++){
        acc[m][n] = __builtin_amdgcn_mfma_f32_16x16x32_bf16(fah[m], fbh[n], acc[m][n], 0,0,0);
        acc[m][n] = __builtin_amdgcn_mfma_f32_16x16x32_bf16(fah[m], fbl[n], acc[m][n], 0,0,0);
        if constexpr (ALO)
          acc[m][n] = __builtin_amdgcn_mfma_f32_16x16x32_bf16(fal[m], fbh[n], acc[m][n], 0,0,0);
      }
  }
#undef LD_TILE
#undef ST_F32
#undef ST_TILE

  // ---- epilogue (C layout: col=lane&15, row=(lane>>4)*4+reg) ----
  if constexpr (OMODE==0) {
    float* out = (float*)outp;
    float bb[4];
    #pragma unroll
    for (int n=0;n<4;n++) bb[n] = bias[br0 + wc*64 + n*16 + c];
    #pragma unroll
    for (int m=0;m<4;m++)
      #pragma unroll
      for (int r=0;r<4;r++){
        const int rg = ar0 + wr*64 + m*16 + g*4 + r;
        #pragma unroll
        for (int n=0;n<4;n++)
          out[(size_t)rg*D_ + br0 + wc*64 + n*16 + c] = acc[m][n][r] + bb[n];
      }
  } else if constexpr (OMODE==1) {
    u16* out = (u16*)outp;
    float bb[4];
    #pragma unroll
    for (int n=0;n<4;n++) bb[n] = bias[br0 + wc*64 + n*16 + c];
    #pragma unroll
    for (int m=0;m<4;m++)
      #pragma unroll
      for (int r=0;r<4;r++){
        const int rg = ar0 + wr*64 + m*16 + g*4 + r;
        const int batch = rg >> 11, s = rg & (S_-1);
        #pragma unroll
        for (int n=0;n<4;n++){
          const int col = br0 + wc*64 + n*16 + c;
          const int hh = col >> 6, dk = col & 63;
          out[((size_t)(batch*H_ + hh)*S_ + s)*DK_ + dk] = f2bf(acc[m][n][r] + bb[n]);
        }
      }
  } else {  // OMODE==2: V^T [bh][dk][s]
    u16* out = (u16*)outp;
    #pragma unroll
    for (int m=0;m<4;m++)
      #pragma unroll
      for (int r=0;r<4;r++){
        const int dkg = ar0 + wr*64 + m*16 + g*4 + r;   // over W rows (768)
        const int hh = dkg >> 6, dkl = dkg & 63;
        const float bb = bias[dkg];
        #pragma unroll
        for (int n=0;n<4;n++){
          const int sg = br0 + wc*64 + n*16 + c;        // over X rows (4096)
          const int batch = sg >> 11, s = sg & (S_-1);
          out[((size_t)(batch*H_ + hh)*DK_ + dkl)*S_ + s] = f2bf(acc[m][n][r] + bb);
        }
      }
  }
}

__global__ __launch_bounds__(256,2) void proj_qkv(
    const u16* __restrict__ scr,
    const float* __restrict__ bq, const float* __restrict__ bk, const float* __restrict__ bv,
    u16* __restrict__ qkv)
{
  const int z = blockIdx.z;
  u16* out = qkv + (size_t)z * ((size_t)BH_*S_*DK_);
  const u16* Xh = scr + (size_t)z*XN_;
  const u16* Xl = scr + (size_t)(3+z)*XN_;
  const u16* Wh = scr + 6*XN_ + (size_t)z*WN_;
  const u16* Wl = scr + 6*XN_ + 3*WN_ + (size_t)z*WN_;
  const float* bias = (z==0)?bq:(z==1)?bk:bv;
  if (z==2) gemmM<true,true,2>(Wh, Wl, Xh, Xl, nullptr, bias, (void*)out);
  else      gemmM<true,true,1>(Xh, Xl, Wh, Wl, nullptr, bias, (void*)out);
}

__global__ __launch_bounds__(256,2) void proj_o(
    const u16* __restrict__ Xc, const float* __restrict__ Wo, const float* __restrict__ bo,
    float* __restrict__ out)
{
  gemmM<false,false,0>(Xc, nullptr, nullptr, nullptr, Wo, bo, (void*)out);
}

// ---------------- attention (MFMA, double-buffered, 1 barrier/tile, named-reg staging) ----------------
__global__ __launch_bounds__(256,3) void attn(const u16* __restrict__ qkv,
                                              const u64* __restrict__ mbits,
                                              float* __restrict__ la, u16* __restrict__ ctx)
{
  const int bh = blockIdx.y;
  const int q0 = blockIdx.x * 64;
  const int b = bh / H_;
  const int h = bh - b*H_;
  const u16* Qp = qkv + (size_t)bh * S_ * DK_;             // [S][DK]
  const u16* Kp = qkv + (size_t)(BH_ + bh) * S_ * DK_;     // [S][DK]
  const u16* Vt = qkv + (size_t)(2*BH_ + bh) * S_ * DK_;   // [DK][S]
  const u64* Mb = mbits + (size_t)b * S_ * (S_/64);

  const int tid  = threadIdx.x;
  const int w    = tid >> 6;
  const int lane = tid & 63;
  const int g    = lane >> 4;
  const int c    = lane & 15;
  const int srow = tid >> 3;        // 0..31
  const int scol = (tid & 7) * 8;   // u16 units 0..56

  __shared__ u16 KsB[2][64][72];
  __shared__ u16 VsB[2][64][72];
  __shared__ u16 Ps[4][16][72];     // wave-private strips

  // ---- Q -> VsB[0] (temp) -> A-fragments ----
  {
    uint4 qa = *(const uint4*)(Qp + (size_t)(q0+srow)*DK_ + scol);
    uint4 qb = *(const uint4*)(Qp + (size_t)(q0+32+srow)*DK_ + scol);
    *(uint4*)&VsB[0][srow][scol] = qa;
    *(uint4*)&VsB[0][srow+32][scol] = qb;
  }
  __syncthreads();
  const bf16x8 qf0 = *(const bf16x8*)&VsB[0][w*16 + c][g*8];
  const bf16x8 qf1 = *(const bf16x8*)&VsB[0][w*16 + c][g*8 + 32];

  float mt[4], lt[4];
  #pragma unroll
  for (int r=0;r<4;r++){ mt[r] = MINIT; lt[r] = 0.f; }

  // ---- pass A: online (m,l), K double-buffered ----
  {
    uint4 ka = *(const uint4*)(Kp + (size_t)srow*DK_ + scol);
    uint4 kb = *(const uint4*)(Kp + (size_t)(32+srow)*DK_ + scol);
    *(uint4*)&KsB[0][srow][scol] = ka;
    *(uint4*)&KsB[0][srow+32][scol] = kb;
    for (int t=0; t<S_/64; ++t){
      __syncthreads();                         // KsB[t&1] visible; prior reads of other buf done
      if (t < S_/64-1){
        const u16* kp = Kp + (size_t)(t+1)*64*DK_;
        ka = *(const uint4*)(kp + (size_t)srow*DK_ + scol);
        kb = *(const uint4*)(kp + (size_t)(32+srow)*DK_ + scol);
      }
      u64 mw[4];
      #pragma unroll
      for (int r=0;r<4;r++) mw[r] = Mb[(size_t)(q0 + w*16 + g*4 + r)*(S_/64) + t];

      f32x4 sc[4];
      #pragma unroll
      for (int nt=0; nt<4; nt++){
        const bf16x8 kf0 = *(const bf16x8*)&KsB[t&1][nt*16 + c][g*8];
        const bf16x8 kf1 = *(const bf16x8*)&KsB[t&1][nt*16 + c][g*8 + 32];
        f32x4 z = {0.f,0.f,0.f,0.f};
        z      = __builtin_amdgcn_mfma_f32_16x16x32_bf16(qf0, kf0, z, 0,0,0);
        sc[nt] = __builtin_amdgcn_mfma_f32_16x16x32_bf16(qf1, kf1, z, 0,0,0);
      }
      #pragma unroll
      for (int r=0;r<4;r++){
        const float sv0 = ((mw[r] >> (c    )) & 1) ? sc[0][r]*SCALE : NEGV;
        const float sv1 = ((mw[r] >> (c+16)) & 1) ? sc[1][r]*SCALE : NEGV;
        const float sv2 = ((mw[r] >> (c+32)) & 1) ? sc[2][r]*SCALE : NEGV;
        const float sv3 = ((mw[r] >> (c+48)) & 1) ? sc[3][r]*SCALE : NEGV;
        const float cm = fmaxf(fmaxf(sv0,sv1), fmaxf(sv2,sv3));
        if (!__all(cm <= mt[r])){              // exact defer: rescale only if any lane's max grew
          const float mn = fmaxf(mt[r], cm);
          lt[r] *= __expf(mt[r]-mn);
          mt[r] = mn;
        }
        lt[r] += __expf(sv0-mt[r]) + __expf(sv1-mt[r]) + __expf(sv2-mt[r]) + __expf(sv3-mt[r]);
      }
      if (t < S_/64-1){
        *(uint4*)&KsB[(t+1)&1][srow][scol] = ka;
        *(uint4*)&KsB[(t+1)&1][srow+32][scol] = kb;
      }
    }
  }

  // ---- merge (m,l) across the 16 lanes of each group ----
  float ml[4];
  #pragma unroll
  for (int r=0;r<4;r++){
    float m = mt[r], l = lt[r];
    #pragma unroll
    for (int st=1; st<16; st<<=1){
      const float m2 = __shfl_xor(m, st);
      const float l2 = __shfl_xor(l, st);
      const float mn = fmaxf(m, m2);
      l = l*__expf(m-mn) + l2*__expf(m2-mn);
      m = mn;
    }
    ml[r] = m + __logf(fmaxf(l, 1e-30f));
  }

  // ---- pass B: recompute scores, emit log_attn, MFMA P.V; K/V double-buffered ----
  f32x4 o[4];
  #pragma unroll
  for (int nt=0;nt<4;nt++) o[nt] = (f32x4){0.f,0.f,0.f,0.f};

  {
    uint4 ka = *(const uint4*)(Kp + (size_t)srow*DK_ + scol);
    uint4 kb = *(const uint4*)(Kp + (size_t)(32+srow)*DK_ + scol);
    uint4 va = *(const uint4*)(Vt + (size_t)srow*S_ + scol);
    uint4 vb = *(const uint4*)(Vt + (size_t)(32+srow)*S_ + scol);
    *(uint4*)&KsB[0][srow][scol] = ka;   *(uint4*)&KsB[0][srow+32][scol] = kb;
    *(uint4*)&VsB[0][srow][scol] = va;   *(uint4*)&VsB[0][srow+32][scol] = vb;
    for (int t=0; t<S_/64; ++t){
      __syncthreads();
      if (t < S_/64-1){
        const u16* kp = Kp + (size_t)(t+1)*64*DK_;
        const u16* vp = Vt + (size_t)(t+1)*64;
        ka = *(const uint4*)(kp + (size_t)srow*DK_ + scol);
        kb = *(const uint4*)(kp + (size_t)(32+srow)*DK_ + scol);
        va = *(const uint4*)(vp + (size_t)srow*S_ + scol);
        vb = *(const uint4*)(vp + (size_t)(32+srow)*S_ + scol);
      }
      u64 mw[4];
      #pragma unroll
      for (int r=0;r<4;r++) mw[r] = Mb[(size_t)(q0 + w*16 + g*4 + r)*(S_/64) + t];

      f32x4 sc[4];
      #pragma unroll
      for (int nt=0; nt<4; nt++){
        const bf16x8 kf0 = *(const bf16x8*)&KsB[t&1][nt*16 + c][g*8];
        const bf16x8 kf1 = *(const bf16x8*)&KsB[t&1][nt*16 + c][g*8 + 32];
        f32x4 z = {0.f,0.f,0.f,0.f};
        z      = __builtin_amdgcn_mfma_f32_16x16x32_bf16(qf0, kf0, z, 0,0,0);
        sc[nt] = __builtin_amdgcn_mfma_f32_16x16x32_bf16(qf1, kf1, z, 0,0,0);
      }
      float lvv[4][4];
      #pragma unroll
      for (int r=0;r<4;r++){
        #pragma unroll
        for (int nt=0;nt<4;nt++){
          const float s  = ((mw[r] >> (nt*16 + c)) & 1) ? sc[nt][r]*SCALE : NEGV;
          const float lv = fminf(s - ml[r], 0.f);
          lvv[r][nt] = lv;
          Ps[w][g*4+r][nt*16 + c] = f2bf(__expf(lv));
        }
      }
      // Ps is wave-private: per-wave DS ordering + compiler lgkmcnt fence the RAW
      const bf16x8 pf0 = *(const bf16x8*)&Ps[w][c][g*8];
      const bf16x8 pf1 = *(const bf16x8*)&Ps[w][c][g*8 + 32];
      #pragma unroll
      for (int nt=0; nt<4; nt++){
        const bf16x8 vf0 = *(const bf16x8*)&VsB[t&1][nt*16 + c][g*8];
        const bf16x8 vf1 = *(const bf16x8*)&VsB[t&1][nt*16 + c][g*8 + 32];
        o[nt] = __builtin_amdgcn_mfma_f32_16x16x32_bf16(pf0, vf0, o[nt], 0,0,0);
        o[nt] = __builtin_amdgcn_mfma_f32_16x16x32_bf16(pf1, vf1, o[nt], 0,0,0);
      }
      #pragma unroll
      for (int r=0;r<4;r++){
        float* lrow = la + ((size_t)bh*S_ + q0 + w*16 + g*4 + r)*S_ + (size_t)t*64 + c;
        #pragma unroll
        for (int nt=0;nt<4;nt++) lrow[nt*16] = lvv[r][nt];
      }
      if (t < S_/64-1){
        *(uint4*)&KsB[(t+1)&1][srow][scol] = ka;   *(uint4*)&KsB[(t+1)&1][srow+32][scol] = kb;
        *(uint4*)&VsB[(t+1)&1][srow][scol] = va;   *(uint4*)&VsB[(t+1)&1][srow+32][scol] = vb;
      }
    }
  }

  #pragma unroll
  for (int r=0;r<4;r++){
    const int qi = q0 + w*16 + g*4 + r;
    u16* crow = ctx + ((size_t)b*S_ + qi)*D_ + h*DK_ + c;
    #pragma unroll
    for (int nt=0;nt<4;nt++) crow[nt*16] = f2bf(o[nt][r]);
  }
}

extern "C" void kernel_launch(void* const* d_in, const int* in_sizes, int n_in,
                              void* d_out, int out_size, void* d_ws, size_t ws_size,
                              hipStream_t stream)
{
  const float* query = (const float*)d_in[0];
  const float* key   = (const float*)d_in[1];
  const float* value = (const float*)d_in[2];
  const int* mask    = (const int*)d_in[3];
  const float* Wq = (const float*)d_in[4];  const float* bq = (const float*)d_in[5];
  const float* Wk = (const float*)d_in[6];  const float* bk = (const float*)d_in[7];
  const float* Wv = (const float*)d_in[8];  const float* bv = (const float*)d_in[9];
  const float* Wo = (const float*)d_in[10]; const float* bo = (const float*)d_in[11];

  float* out = (float*)d_out;                      // [B,S,D] f32
  float* la  = out + (size_t)B_*S_*D_;             // [B,H,S,S] f32
  u16* qkvws = (u16*)d_ws;                         // Q,K: [BH,S,DK]; V: [BH,DK,S] bf16
  u16* ctx = qkvws + (size_t)3*BH_*S_*DK_;         // [B,S,D] bf16
  // scr lives in la (consumed by proj_qkv before attn overwrites la);
  // mbits lives in out (consumed by attn before proj_o overwrites out). Same-stream ordering.
  u16* scr = (u16*)la;
  u64* mbits = (u64*)out;

  prep    <<<dim3(768,6,1),    dim3(256,1,1), 0, stream>>>(query,key,value,Wq,Wk,Wv,scr);
  maskpack<<<dim3(512,1,1),    dim3(256,1,1), 0, stream>>>(mask, mbits);
  proj_qkv<<<dim3(32,6,3),     dim3(256,1,1), 0, stream>>>(scr, bq,bk,bv, qkvws);
  attn    <<<dim3(S_/64,BH_,1),dim3(256,1,1), 0, stream>>>(qkvws, mbits, la, ctx);
  proj_o  <<<dim3(32,6,1),     dim3(256,1,1), 0, stream>>>(ctx, Wo, bo, out);
}